// Round 3
// baseline (190.942 us; speedup 1.0000x reference)
//
#include <hip/hip_runtime.h>

typedef unsigned short u16;
typedef __bf16 bf16x8 __attribute__((ext_vector_type(8)));
typedef float f32x4 __attribute__((ext_vector_type(4)));
typedef short s16x4 __attribute__((ext_vector_type(4)));
typedef short s16x8 __attribute__((ext_vector_type(8)));

#define NTOK 32768
#define SCALE_F 0.17677669529663689f

__device__ __forceinline__ u16 f2bf(float f){
  unsigned u = __builtin_bit_cast(unsigned, f);
  u += 0x7fffu + ((u>>16)&1u);
  return (u16)(u>>16);
}

// ============ K1: k/v projection (transposed) + exp(k) + ctx^T + S1 ============
// grid (nchunk, 8b), 256 thr. chunk = siters*64 tokens.
// Proj computed as D[n][ch] = xT-rows x wqkv-rows (A<->B swap) so ri runs along n
// -> ek/vl stores are b64. ctx^T and S1 accumulate via MFMA (S1 via ones-row).
__global__ __launch_bounds__(256) void k1_ctx(const float* __restrict__ x,
    const float* __restrict__ wqkv, float* __restrict__ ctxP, float* __restrict__ s1P,
    int siters)
{
  const int b = blockIdx.y, chunk = blockIdx.x, nchunk = gridDim.x;
  const int t = threadIdx.x, w = t>>6, l = t&63, lr = l&15, lg = l>>4;
  __shared__ u16 xT[64*72];    // [n][c]
  __shared__ u16 ek[128*72];   // [k-ch][n]  exp(k) bf16
  __shared__ u16 vl[128*72];   // [v-ch][n]  v bf16

  // B-frags: wqkv rows 128 + w*64 + ct*16 + lr (col=ch, k=c contiguous)
  bf16x8 bw[4][2];
  #pragma unroll
  for (int ct=0;ct<4;ct++)
    #pragma unroll
    for (int ks=0;ks<2;ks++){
      const float* src = wqkv + (128 + w*64 + ct*16 + lr)*64 + ks*32 + lg*8;
      #pragma unroll
      for (int j=0;j<8;j++) ((u16*)&bw[ct][ks])[j] = f2bf(src[j]);
    }
  bf16x8 ones;
  #pragma unroll
  for (int j=0;j<8;j++) ((u16*)&ones)[j] = 0x3F80;

  f32x4 ctx[2][2]; f32x4 s1a[2];
  #pragma unroll
  for (int i=0;i<2;i++){
    s1a[i] = f32x4{0.f,0.f,0.f,0.f};
    #pragma unroll
    for (int j=0;j<2;j++) ctx[i][j] = f32x4{0.f,0.f,0.f,0.f};
  }
  const float* xb = x + (long)b*64*NTOK;
  u16* dst = (w<2) ? ek : vl;
  const int chb = (w&1)*64;
  const bool isk = (w<2);
  const int sn = t&63, cg = (t>>6)*16;

  for (int s=0; s<siters; s++) {
    const int n0 = (chunk*siters + s)*64;
    __syncthreads();
    { // stage x[64c][64n] -> xT[n][c]: 16 coalesced loads along c, 2x b128 LDS writes
      u16 tmp[16];
      #pragma unroll
      for (int i=0;i<16;i++) tmp[i] = f2bf(xb[(long)(cg+i)*NTOK + n0 + sn]);
      *(s16x8*)&xT[sn*72 + cg]     = *(s16x8*)&tmp[0];
      *(s16x8*)&xT[sn*72 + cg + 8] = *(s16x8*)&tmp[8];
    }
    __syncthreads();
    f32x4 acc[4][4];
    #pragma unroll
    for (int rt=0;rt<4;rt++)
      #pragma unroll
      for (int ct=0;ct<4;ct++) acc[rt][ct] = f32x4{0.f,0.f,0.f,0.f};
    #pragma unroll
    for (int ks=0;ks<2;ks++){
      bf16x8 af[4];
      #pragma unroll
      for (int rt=0;rt<4;rt++)
        af[rt] = *(const bf16x8*)&xT[(rt*16+lr)*72 + ks*32 + lg*8];
      #pragma unroll
      for (int rt=0;rt<4;rt++)
        #pragma unroll
        for (int ct=0;ct<4;ct++)
          acc[rt][ct] = __builtin_amdgcn_mfma_f32_16x16x32_bf16(af[rt], bw[ct][ks], acc[rt][ct], 0,0,0);
    }
    // D[row=n=rt*16+lg*4+ri][col=ch=ct*16+lr]: store b64 along n
    #pragma unroll
    for (int ct=0;ct<4;ct++){
      const int row = chb + ct*16 + lr;
      #pragma unroll
      for (int rt=0;rt<4;rt++){
        s16x4 p;
        #pragma unroll
        for (int ri=0;ri<4;ri++){
          const float v = acc[rt][ct][ri];
          p[ri] = (short)f2bf(isk ? __expf(v) : v);
        }
        *(s16x4*)&dst[row*72 + rt*16 + lg*4] = p;
      }
    }
    __syncthreads();
    // ctx^T[e][d] += v[e][n]*ek[d][n]; S1[d] += sum_n ek[d][n] via ones-row
    #pragma unroll
    for (int ks=0;ks<2;ks++){
      bf16x8 bd[2];
      #pragma unroll
      for (int cd=0;cd<2;cd++)
        bd[cd] = *(const bf16x8*)&ek[(w*32 + cd*16 + lr)*72 + ks*32 + lg*8];
      #pragma unroll
      for (int re=0;re<2;re++){
        bf16x8 a = *(const bf16x8*)&vl[(w*32 + re*16 + lr)*72 + ks*32 + lg*8];
        #pragma unroll
        for (int cd=0;cd<2;cd++)
          ctx[re][cd] = __builtin_amdgcn_mfma_f32_16x16x32_bf16(a, bd[cd], ctx[re][cd], 0,0,0);
      }
      #pragma unroll
      for (int cd=0;cd<2;cd++)
        s1a[cd] = __builtin_amdgcn_mfma_f32_16x16x32_bf16(ones, bd[cd], s1a[cd], 0,0,0);
    }
  }
  float* cp = ctxP + (((long)b*nchunk + chunk)*4 + w)*1024;
  #pragma unroll
  for (int re=0;re<2;re++)
    #pragma unroll
    for (int cd=0;cd<2;cd++)
      #pragma unroll
      for (int ri=0;ri<4;ri++){
        const int e = re*16 + lg*4 + ri, d = cd*16 + lr;
        cp[e*32 + d] = ctx[re][cd][ri];
      }
  if (lg==0){
    #pragma unroll
    for (int cd=0;cd<2;cd++)
      s1P[((long)b*nchunk + chunk)*128 + w*32 + cd*16 + lr] = s1a[cd][0];
  }
}

// ============ K2: reduce partials, build W2 = SCALE*w_out*ctx^T/S1 ============
// grid (4 heads, 8 b), 256 thr.
__global__ __launch_bounds__(256) void k2_w2(const float* __restrict__ ctxP,
    const float* __restrict__ s1P, const float* __restrict__ wout, u16* __restrict__ W2,
    int nchunk)
{
  const int b = blockIdx.y, h = blockIdx.x, t = threadIdx.x;
  __shared__ float cs[1024];   // ctx^T[e][d]
  __shared__ float s1s[32];
  const float* base = ctxP + (long)b*nchunk*4096 + h*1024 + t*4;
  float a0=0.f,a1=0.f,a2=0.f,a3=0.f;
  for (int ch=0; ch<nchunk; ch++){
    f32x4 p4 = *(const f32x4*)(base + (long)ch*4096);
    a0 += p4[0]; a1 += p4[1]; a2 += p4[2]; a3 += p4[3];
  }
  cs[t*4+0]=a0; cs[t*4+1]=a1; cs[t*4+2]=a2; cs[t*4+3]=a3;
  if (t < 32){
    float s = 0.f;
    for (int ch=0; ch<nchunk; ch++) s += s1P[((long)b*nchunk+ch)*128 + h*32 + t];
    s1s[t] = s;
  }
  __syncthreads();
  const int d = t & 31;
  const float rinv = SCALE_F / s1s[d];
  #pragma unroll
  for (int oi=0; oi<8; oi++){
    const int o = (t>>5)*8 + oi;
    float acc = 0.f;
    #pragma unroll
    for (int e=0;e<32;e++) acc += wout[o*128 + h*32 + e] * cs[e*32 + d];
    W2[((long)b*64 + o)*128 + h*32 + d] = f2bf(acc * rinv);
  }
}

// ============ K3: q-proj + softmax_D + y = W2@qsm + b_out -> d_out, stats ============
// grid (512 tiles of 64 tokens, 8 b), 256 thr.
__global__ __launch_bounds__(256) void k3_y(const float* __restrict__ x,
    const float* __restrict__ wqkv, const u16* __restrict__ W2,
    const float* __restrict__ bout, float* __restrict__ y, float* __restrict__ ysum)
{
  const int b = blockIdx.y, blk = blockIdx.x;
  const int t = threadIdx.x, w = t>>6, l = t&63, lr = l&15, lg = l>>4;
  const int n0 = blk*64;
  __shared__ u16 xT[64*72];     // [n][c]
  __shared__ u16 qs[64*136];    // [n][ch] softmaxed q bf16
  __shared__ float red[8];
  const float* xb = x + (long)b*64*NTOK;

  bf16x8 qfr[2][2];   // q rows w*32 .. w*32+31
  #pragma unroll
  for (int rt=0;rt<2;rt++)
    #pragma unroll
    for (int ks=0;ks<2;ks++){
      const float* src = wqkv + (w*32 + rt*16 + lr)*64 + ks*32 + lg*8;
      #pragma unroll
      for (int j=0;j<8;j++) ((u16*)&qfr[rt][ks])[j] = f2bf(src[j]);
    }

  { // stage x[64c][64n] -> xT[n][c]: coalesced loads along c, b128 LDS writes
    const int sn = t&63, cg = (t>>6)*16;
    u16 tmp[16];
    #pragma unroll
    for (int i=0;i<16;i++) tmp[i] = f2bf(xb[(long)(cg+i)*NTOK + n0 + sn]);
    *(s16x8*)&xT[sn*72 + cg]     = *(s16x8*)&tmp[0];
    *(s16x8*)&xT[sn*72 + cg + 8] = *(s16x8*)&tmp[8];
  }
  __syncthreads();
  f32x4 qa[2][4];
  #pragma unroll
  for (int rt=0;rt<2;rt++)
    #pragma unroll
    for (int ct=0;ct<4;ct++) qa[rt][ct] = f32x4{0.f,0.f,0.f,0.f};
  #pragma unroll
  for (int ks=0;ks<2;ks++){
    bf16x8 bfr[4];
    #pragma unroll
    for (int ct=0;ct<4;ct++)
      bfr[ct] = *(const bf16x8*)&xT[(ct*16+lr)*72 + ks*32 + lg*8];
    #pragma unroll
    for (int rt=0;rt<2;rt++){
      #pragma unroll
      for (int ct=0;ct<4;ct++)
        qa[rt][ct] = __builtin_amdgcn_mfma_f32_16x16x32_bf16(qfr[rt][ks], bfr[ct], qa[rt][ct], 0,0,0);
    }
  }
  // softmax over 32 head-dim rows per token col (in-lane + shfl over lg groups)
  #pragma unroll
  for (int ct=0;ct<4;ct++){
    float e[2][4]; float p = 0.f;
    #pragma unroll
    for (int rt=0;rt<2;rt++)
      #pragma unroll
      for (int ri=0;ri<4;ri++){ e[rt][ri] = __expf(qa[rt][ct][ri]); p += e[rt][ri]; }
    p += __shfl_xor(p, 16, 64);
    p += __shfl_xor(p, 32, 64);
    const float rinv = 1.f/p;
    const int nn = ct*16 + lr;
    #pragma unroll
    for (int rt=0;rt<2;rt++){
      s16x4 pk;
      #pragma unroll
      for (int ri=0;ri<4;ri++) pk[ri] = (short)f2bf(e[rt][ri]*rinv);
      *(s16x4*)&qs[nn*136 + w*32 + rt*16 + lg*4] = pk;
    }
  }
  __syncthreads();
  f32x4 ya[4];
  #pragma unroll
  for (int rt=0;rt<4;rt++) ya[rt] = f32x4{0.f,0.f,0.f,0.f};
  #pragma unroll
  for (int ks=0;ks<4;ks++){
    bf16x8 bq = *(const bf16x8*)&qs[(w*16+lr)*136 + ks*32 + lg*8];
    #pragma unroll
    for (int rt=0;rt<4;rt++){
      bf16x8 a = *(const bf16x8*)(W2 + (long)b*8192 + (rt*16+lr)*128 + ks*32 + lg*8);
      ya[rt] = __builtin_amdgcn_mfma_f32_16x16x32_bf16(a, bq, ya[rt], 0,0,0);
    }
  }
  float sum=0.f, ss=0.f;
  float* yb = y + (long)b*64*NTOK;
  #pragma unroll
  for (int rt=0;rt<4;rt++)
    #pragma unroll
    for (int ri=0;ri<4;ri++){
      const int o = rt*16 + lg*4 + ri;
      const int nn = n0 + w*16 + lr;
      const float val = ya[rt][ri] + bout[o];
      sum += val; ss += val*val;
      yb[(long)o*NTOK + nn] = val;
    }
  #pragma unroll
  for (int off=1; off<64; off<<=1){
    sum += __shfl_xor(sum, off, 64);
    ss  += __shfl_xor(ss,  off, 64);
  }
  if (l==0){ red[w*2] = sum; red[w*2+1] = ss; }
  __syncthreads();
  if (t==0){
    ysum[((long)b*512 + blk)*2]   = red[0]+red[2]+red[4]+red[6];
    ysum[((long)b*512 + blk)*2+1] = red[1]+red[3]+red[5]+red[7];
  }
}

// ============ K3b: per-batch mean / rsqrt(var+eps) ============
__global__ __launch_bounds__(256) void k3b_stats(const float* __restrict__ ysum,
                                                 float* __restrict__ musig)
{
  const int b = blockIdx.x, t = threadIdx.x, w = t>>6, l = t&63;
  float s=0.f, q=0.f;
  for (int i=t; i<512; i+=256){
    s += ysum[((long)b*512+i)*2];
    q += ysum[((long)b*512+i)*2+1];
  }
  #pragma unroll
  for (int off=1; off<64; off<<=1){ s += __shfl_xor(s,off,64); q += __shfl_xor(q,off,64); }
  __shared__ float rs[4], rq[4];
  if (l==0){ rs[w]=s; rq[w]=q; }
  __syncthreads();
  if (t==0){
    const float S = rs[0]+rs[1]+rs[2]+rs[3];
    const float Q = rq[0]+rq[1]+rq[2]+rq[3];
    const float inv_n = 1.f/2097152.f;
    const float mu = S*inv_n;
    const float var = Q*inv_n - mu*mu;
    musig[b*2]   = mu;
    musig[b*2+1] = rsqrtf(var + 1e-5f);
  }
}

// ============ K4: normalize + affine, in place on d_out (f32) ============
__global__ __launch_bounds__(256) void k4_norm(float* __restrict__ y,
    const float* __restrict__ musig, const float* __restrict__ gamma,
    const float* __restrict__ beta)
{
  const long idx = ((long)blockIdx.x*256 + threadIdx.x)*4;
  const int b = (int)(idx >> 21);
  const int c = (int)((idx >> 15) & 63);
  const float mu = musig[b*2], inv = musig[b*2+1];
  const float g = gamma[c]*inv, be = beta[c];
  f32x4 v4 = *(const f32x4*)(y + idx);
  #pragma unroll
  for (int j=0;j<4;j++) v4[j] = (v4[j] - mu)*g + be;
  *(f32x4*)(y + idx) = v4;
}

extern "C" void kernel_launch(void* const* d_in, const int* in_sizes, int n_in,
                              void* d_out, int out_size, void* d_ws, size_t ws_size,
                              hipStream_t stream) {
  const float* x     = (const float*)d_in[0];
  const float* wqkv  = (const float*)d_in[1];
  const float* wout  = (const float*)d_in[2];
  const float* bout  = (const float*)d_in[3];
  const float* gamma = (const float*)d_in[4];
  const float* beta  = (const float*)d_in[5];
  float* out = (float*)d_out;
  char* ws = (char*)d_ws;

  // adaptive k1 parallelism: 128 chunks needs ~17.5MB; fall back to 64 (known-good 8.9MB)
  int nchunk, siters;
  size_t need128 = (size_t)131072*128 + (size_t)4096*128 + 131072 + 32768 + 64;
  if (ws_size >= need128) { nchunk = 128; siters = 4; }
  else if (ws_size >= (size_t)131072*64 + (size_t)4096*64 + 131072 + 32768 + 64) { nchunk = 64; siters = 8; }
  else return;

  size_t off = 0;
  float* ctxP = (float*)(ws + off); off += (size_t)131072*nchunk;  // [8][nchunk][4][1024] f32
  float* s1P  = (float*)(ws + off); off += (size_t)4096*nchunk;    // [8][nchunk][128] f32
  u16*  W2    = (u16*) (ws + off); off += 131072;                  // [8][64][128] bf16
  float* ysum = (float*)(ws + off); off += 32768;                  // [8][512][2] f32
  float* musig= (float*)(ws + off);                                // [8][2] f32

  k1_ctx   <<<dim3(nchunk,8), 256, 0, stream>>>(x, wqkv, ctxP, s1P, siters);
  k2_w2    <<<dim3(4,8),  256, 0, stream>>>(ctxP, s1P, wout, W2, nchunk);
  k3_y     <<<dim3(512,8),256, 0, stream>>>(x, wqkv, W2, bout, out, ysum);
  k3b_stats<<<8,          256, 0, stream>>>(ysum, musig);
  k4_norm  <<<16384,      256, 0, stream>>>(out, musig, gamma, beta);
}

// Round 4
// 108.484 us; speedup vs baseline: 1.7601x; 1.7601x over previous
//
#include <hip/hip_runtime.h>

typedef unsigned short u16;
typedef __bf16 bf16x8 __attribute__((ext_vector_type(8)));
typedef float f32x4 __attribute__((ext_vector_type(4)));
typedef short s16x4 __attribute__((ext_vector_type(4)));
typedef short s16x8 __attribute__((ext_vector_type(8)));

#define NTOK 32768
#define SCALE_F 0.17677669529663689f

__device__ __forceinline__ u16 f2bf(float f){
  unsigned u = __builtin_bit_cast(unsigned, f);
  u += 0x7fffu + ((u>>16)&1u);
  return (u16)(u>>16);
}
__device__ __forceinline__ float bf2f(u16 u){
  unsigned v = ((unsigned)u)<<16;
  return __builtin_bit_cast(float, v);
}

// ============ K1: k/v proj (transposed) + exp(k) + ctx^T + S1, atomic-reduced ============
// grid (128, 8b), 256 thr, siters=4 subtiles of 64 tokens. Prefetched x loads.
// ctx  f32[8][4][32*32] and s1 f32[8][128] are atomically accumulated (pre-zeroed).
__global__ __launch_bounds__(256) void k1_ctx(const float* __restrict__ x,
    const float* __restrict__ wqkv, float* __restrict__ ctx, float* __restrict__ s1,
    int siters)
{
  const int b = blockIdx.y, chunk = blockIdx.x;
  const int t = threadIdx.x, w = t>>6, l = t&63, lr = l&15, lg = l>>4;
  __shared__ u16 xT[64*72];    // [n][c]
  __shared__ u16 ek[128*72];   // [k-ch][n]  exp(k) bf16
  __shared__ u16 vl[128*72];   // [v-ch][n]  v bf16

  // B-frags: wqkv rows 128 + w*64 + ct*16 + lr
  bf16x8 bw[4][2];
  #pragma unroll
  for (int ct=0;ct<4;ct++)
    #pragma unroll
    for (int ks=0;ks<2;ks++){
      const float* src = wqkv + (128 + w*64 + ct*16 + lr)*64 + ks*32 + lg*8;
      #pragma unroll
      for (int j=0;j<8;j++) ((u16*)&bw[ct][ks])[j] = f2bf(src[j]);
    }
  bf16x8 ones;
  #pragma unroll
  for (int j=0;j<8;j++) ((u16*)&ones)[j] = 0x3F80;

  f32x4 ctxa[2][2]; f32x4 s1a[2];
  #pragma unroll
  for (int i=0;i<2;i++){
    s1a[i] = f32x4{0.f,0.f,0.f,0.f};
    #pragma unroll
    for (int j=0;j<2;j++) ctxa[i][j] = f32x4{0.f,0.f,0.f,0.f};
  }
  const float* xb = x + (long)b*64*NTOK;
  u16* dst = (w<2) ? ek : vl;
  const int chb = (w&1)*64;
  const bool isk = (w<2);
  const int sn = t&63, cg = (t>>6)*16;

  // prologue: prefetch subtile 0
  float tmpf[16];
  {
    const int n0 = chunk*siters*64;
    #pragma unroll
    for (int i=0;i<16;i++) tmpf[i] = xb[(long)(cg+i)*NTOK + n0 + sn];
  }

  for (int s=0; s<siters; s++) {
    { // write prefetched x -> xT[n][c]
      u16 tmp[16];
      #pragma unroll
      for (int i=0;i<16;i++) tmp[i] = f2bf(tmpf[i]);
      *(s16x8*)&xT[sn*72 + cg]     = *(s16x8*)&tmp[0];
      *(s16x8*)&xT[sn*72 + cg + 8] = *(s16x8*)&tmp[8];
    }
    __syncthreads();
    if (s+1 < siters){ // prefetch next subtile (consumed next iter)
      const int n0 = (chunk*siters + s+1)*64;
      #pragma unroll
      for (int i=0;i<16;i++) tmpf[i] = xb[(long)(cg+i)*NTOK + n0 + sn];
    }
    f32x4 acc[4][4];
    #pragma unroll
    for (int rt=0;rt<4;rt++)
      #pragma unroll
      for (int ct=0;ct<4;ct++) acc[rt][ct] = f32x4{0.f,0.f,0.f,0.f};
    #pragma unroll
    for (int ks=0;ks<2;ks++){
      bf16x8 af[4];
      #pragma unroll
      for (int rt=0;rt<4;rt++)
        af[rt] = *(const bf16x8*)&xT[(rt*16+lr)*72 + ks*32 + lg*8];
      #pragma unroll
      for (int rt=0;rt<4;rt++)
        #pragma unroll
        for (int ct=0;ct<4;ct++)
          acc[rt][ct] = __builtin_amdgcn_mfma_f32_16x16x32_bf16(af[rt], bw[ct][ks], acc[rt][ct], 0,0,0);
    }
    // D[row=n=rt*16+lg*4+ri][col=ch=ct*16+lr]: b64 stores along n
    #pragma unroll
    for (int ct=0;ct<4;ct++){
      const int row = chb + ct*16 + lr;
      #pragma unroll
      for (int rt=0;rt<4;rt++){
        s16x4 p;
        #pragma unroll
        for (int ri=0;ri<4;ri++){
          const float v = acc[rt][ct][ri];
          p[ri] = (short)f2bf(isk ? __expf(v) : v);
        }
        *(s16x4*)&dst[row*72 + rt*16 + lg*4] = p;
      }
    }
    __syncthreads();
    // ctx^T[e][d] += v[e][n]*ek[d][n]; S1[d] via ones-row MFMA
    #pragma unroll
    for (int ks=0;ks<2;ks++){
      bf16x8 bd[2];
      #pragma unroll
      for (int cd=0;cd<2;cd++)
        bd[cd] = *(const bf16x8*)&ek[(w*32 + cd*16 + lr)*72 + ks*32 + lg*8];
      #pragma unroll
      for (int re=0;re<2;re++){
        bf16x8 a = *(const bf16x8*)&vl[(w*32 + re*16 + lr)*72 + ks*32 + lg*8];
        #pragma unroll
        for (int cd=0;cd<2;cd++)
          ctxa[re][cd] = __builtin_amdgcn_mfma_f32_16x16x32_bf16(a, bd[cd], ctxa[re][cd], 0,0,0);
      }
      #pragma unroll
      for (int cd=0;cd<2;cd++)
        s1a[cd] = __builtin_amdgcn_mfma_f32_16x16x32_bf16(ones, bd[cd], s1a[cd], 0,0,0);
    }
  }
  float* cp = ctx + ((long)b*4 + w)*1024;
  #pragma unroll
  for (int re=0;re<2;re++)
    #pragma unroll
    for (int cd=0;cd<2;cd++)
      #pragma unroll
      for (int ri=0;ri<4;ri++){
        const int e = re*16 + lg*4 + ri, d = cd*16 + lr;
        atomicAdd(&cp[e*32 + d], ctxa[re][cd][ri]);
      }
  if (lg==0){
    #pragma unroll
    for (int cd=0;cd<2;cd++)
      atomicAdd(&s1[(long)b*128 + w*32 + cd*16 + lr], s1a[cd][0]);
  }
}

// ============ K2: build W2 = SCALE*w_out*ctx^T/S1 (ctx already reduced) ============
// grid (4 heads, 8 b), 256 thr.
__global__ __launch_bounds__(256) void k2_w2(const float* __restrict__ ctx,
    const float* __restrict__ s1, const float* __restrict__ wout, u16* __restrict__ W2)
{
  const int b = blockIdx.y, h = blockIdx.x, t = threadIdx.x;
  __shared__ float cs[1024];   // ctx^T[e][d]
  __shared__ float s1s[32];
  {
    f32x4 p4 = *(const f32x4*)(ctx + ((long)b*4 + h)*1024 + t*4);
    *(f32x4*)&cs[t*4] = p4;
  }
  if (t < 32) s1s[t] = s1[(long)b*128 + h*32 + t];
  __syncthreads();
  const int d = t & 31;
  const float rinv = SCALE_F / s1s[d];
  #pragma unroll
  for (int oi=0; oi<8; oi++){
    const int o = (t>>5)*8 + oi;
    float acc = 0.f;
    #pragma unroll
    for (int e=0;e<32;e++) acc += wout[o*128 + h*32 + e] * cs[e*32 + d];
    W2[((long)b*64 + o)*128 + h*32 + d] = f2bf(acc * rinv);
  }
}

// ============ K3: q-proj + softmax_D + y = W2@qsm + b_out -> d_out, stats ============
// grid (128, 8b), 256 thr; 4 token-tiles of 64 per block. W2 in LDS, x prefetched.
#define K3T 4
__global__ __launch_bounds__(256) void k3_y(const float* __restrict__ x,
    const float* __restrict__ wqkv, const u16* __restrict__ W2,
    const float* __restrict__ bout, float* __restrict__ y, float* __restrict__ ysum)
{
  const int b = blockIdx.y, blk = blockIdx.x;
  const int t = threadIdx.x, w = t>>6, l = t&63, lr = l&15, lg = l>>4;
  __shared__ u16 W2s[64*136];   // [o][ch]
  __shared__ u16 xT[64*72];     // [n][c]
  __shared__ u16 qs[64*136];    // [n][ch] softmaxed q bf16
  __shared__ float red[8];
  const float* xb = x + (long)b*64*NTOK;

  bf16x8 qfr[2][2];   // q rows w*32 .. w*32+31
  #pragma unroll
  for (int rt=0;rt<2;rt++)
    #pragma unroll
    for (int ks=0;ks<2;ks++){
      const float* src = wqkv + (w*32 + rt*16 + lr)*64 + ks*32 + lg*8;
      #pragma unroll
      for (int j=0;j<8;j++) ((u16*)&qfr[rt][ks])[j] = f2bf(src[j]);
    }
  { // stage W2[b] -> LDS once: thread t covers o=t>>2, cols (t&3)*32..+31
    const u16* src = W2 + (long)b*8192 + t*32;
    const int o = t>>2, c0 = (t&3)*32;
    #pragma unroll
    for (int k=0;k<4;k++)
      *(s16x8*)&W2s[o*136 + c0 + k*8] = *(const s16x8*)(src + k*8);
  }
  // prologue: prefetch tile 0
  const int sn = t&63, cg = (t>>6)*16;
  float tmpf[16];
  {
    const int n0 = blk*K3T*64;
    #pragma unroll
    for (int i=0;i<16;i++) tmpf[i] = xb[(long)(cg+i)*NTOK + n0 + sn];
  }
  float sum=0.f, ss=0.f;
  float* yb = y + (long)b*64*NTOK;

  for (int ti=0; ti<K3T; ti++){
    const int n0 = (blk*K3T + ti)*64;
    { // write prefetched x -> xT
      u16 tmp[16];
      #pragma unroll
      for (int i=0;i<16;i++) tmp[i] = f2bf(tmpf[i]);
      *(s16x8*)&xT[sn*72 + cg]     = *(s16x8*)&tmp[0];
      *(s16x8*)&xT[sn*72 + cg + 8] = *(s16x8*)&tmp[8];
    }
    __syncthreads();   // xT ready (also W2s on ti=0)
    if (ti+1 < K3T){
      const int nn0 = n0 + 64;
      #pragma unroll
      for (int i=0;i<16;i++) tmpf[i] = xb[(long)(cg+i)*NTOK + nn0 + sn];
    }
    f32x4 qa[2][4];
    #pragma unroll
    for (int rt=0;rt<2;rt++)
      #pragma unroll
      for (int ct=0;ct<4;ct++) qa[rt][ct] = f32x4{0.f,0.f,0.f,0.f};
    #pragma unroll
    for (int ks=0;ks<2;ks++){
      bf16x8 bfr[4];
      #pragma unroll
      for (int ct=0;ct<4;ct++)
        bfr[ct] = *(const bf16x8*)&xT[(ct*16+lr)*72 + ks*32 + lg*8];
      #pragma unroll
      for (int rt=0;rt<2;rt++)
        #pragma unroll
        for (int ct=0;ct<4;ct++)
          qa[rt][ct] = __builtin_amdgcn_mfma_f32_16x16x32_bf16(qfr[rt][ks], bfr[ct], qa[rt][ct], 0,0,0);
    }
    // softmax over 32 head-dim rows per token col
    #pragma unroll
    for (int ct=0;ct<4;ct++){
      float e[2][4]; float p = 0.f;
      #pragma unroll
      for (int rt=0;rt<2;rt++)
        #pragma unroll
        for (int ri=0;ri<4;ri++){ e[rt][ri] = __expf(qa[rt][ct][ri]); p += e[rt][ri]; }
      p += __shfl_xor(p, 16, 64);
      p += __shfl_xor(p, 32, 64);
      const float rinv = 1.f/p;
      const int nn = ct*16 + lr;
      #pragma unroll
      for (int rt=0;rt<2;rt++){
        s16x4 pk;
        #pragma unroll
        for (int ri=0;ri<4;ri++) pk[ri] = (short)f2bf(e[rt][ri]*rinv);
        *(s16x4*)&qs[nn*136 + w*32 + rt*16 + lg*4] = pk;
      }
    }
    __syncthreads();   // qs ready
    f32x4 ya[4];
    #pragma unroll
    for (int rt=0;rt<4;rt++) ya[rt] = f32x4{0.f,0.f,0.f,0.f};
    #pragma unroll
    for (int ks=0;ks<4;ks++){
      bf16x8 bq = *(const bf16x8*)&qs[(w*16+lr)*136 + ks*32 + lg*8];
      #pragma unroll
      for (int rt=0;rt<4;rt++){
        bf16x8 a = *(const bf16x8*)&W2s[(rt*16+lr)*136 + ks*32 + lg*8];
        ya[rt] = __builtin_amdgcn_mfma_f32_16x16x32_bf16(a, bq, ya[rt], 0,0,0);
      }
    }
    #pragma unroll
    for (int rt=0;rt<4;rt++)
      #pragma unroll
      for (int ri=0;ri<4;ri++){
        const int o = rt*16 + lg*4 + ri;
        const float val = ya[rt][ri] + bout[o];
        sum += val; ss += val*val;
        yb[(long)o*NTOK + n0 + w*16 + lr] = val;
      }
    __syncthreads();   // PV reads done before next iter's xT/qs writes
  }
  #pragma unroll
  for (int off=1; off<64; off<<=1){
    sum += __shfl_xor(sum, off, 64);
    ss  += __shfl_xor(ss,  off, 64);
  }
  if (l==0){ red[w*2] = sum; red[w*2+1] = ss; }
  __syncthreads();
  if (t==0){
    ysum[((long)b*128 + blk)*2]   = red[0]+red[2]+red[4]+red[6];
    ysum[((long)b*128 + blk)*2+1] = red[1]+red[3]+red[5]+red[7];
  }
}

// ============ K3b: per-batch mean / rsqrt(var+eps) ============
__global__ __launch_bounds__(256) void k3b_stats(const float* __restrict__ ysum,
                                                 float* __restrict__ musig)
{
  const int b = blockIdx.x, t = threadIdx.x, w = t>>6, l = t&63;
  float s=0.f, q=0.f;
  if (t < 128){
    s = ysum[((long)b*128+t)*2];
    q = ysum[((long)b*128+t)*2+1];
  }
  #pragma unroll
  for (int off=1; off<64; off<<=1){ s += __shfl_xor(s,off,64); q += __shfl_xor(q,off,64); }
  __shared__ float rs[4], rq[4];
  if (l==0){ rs[w]=s; rq[w]=q; }
  __syncthreads();
  if (t==0){
    const float S = rs[0]+rs[1];
    const float Q = rq[0]+rq[1];
    const float inv_n = 1.f/2097152.f;
    const float mu = S*inv_n;
    const float var = Q*inv_n - mu*mu;
    musig[b*2]   = mu;
    musig[b*2+1] = rsqrtf(var + 1e-5f);
  }
}

// ============ K4: normalize + affine, in place on d_out (f32) ============
__global__ __launch_bounds__(256) void k4_norm(float* __restrict__ y,
    const float* __restrict__ musig, const float* __restrict__ gamma,
    const float* __restrict__ beta)
{
  const long idx = ((long)blockIdx.x*256 + threadIdx.x)*4;
  const int b = (int)(idx >> 21);
  const int c = (int)((idx >> 15) & 63);
  const float mu = musig[b*2], inv = musig[b*2+1];
  const float g = gamma[c]*inv, be = beta[c];
  f32x4 v4 = *(const f32x4*)(y + idx);
  #pragma unroll
  for (int j=0;j<4;j++) v4[j] = (v4[j] - mu)*g + be;
  *(f32x4*)(y + idx) = v4;
}

extern "C" void kernel_launch(void* const* d_in, const int* in_sizes, int n_in,
                              void* d_out, int out_size, void* d_ws, size_t ws_size,
                              hipStream_t stream) {
  const float* x     = (const float*)d_in[0];
  const float* wqkv  = (const float*)d_in[1];
  const float* wout  = (const float*)d_in[2];
  const float* bout  = (const float*)d_in[3];
  const float* gamma = (const float*)d_in[4];
  const float* beta  = (const float*)d_in[5];
  float* out = (float*)d_out;
  char* ws = (char*)d_ws;
  if (ws_size < 300000u) return;

  float* ctx  = (float*)(ws + 0);       // [8][4][1024] f32 = 131072 B
  float* s1   = (float*)(ws + 131072);  // [8][128] f32     = 4096 B
  u16*  W2    = (u16*) (ws + 135168);   // [8][64][128] bf16 = 131072 B
  float* ysum = (float*)(ws + 266240);  // [8][128][2] f32   = 8192 B
  float* musig= (float*)(ws + 274432);  // [8][2] f32

  hipMemsetAsync(ws, 0, 135168, stream);  // zero ctx + s1 accumulators
  k1_ctx   <<<dim3(128,8), 256, 0, stream>>>(x, wqkv, ctx, s1, 4);
  k2_w2    <<<dim3(4,8),   256, 0, stream>>>(ctx, s1, wout, W2);
  k3_y     <<<dim3(128,8), 256, 0, stream>>>(x, wqkv, W2, bout, out, ysum);
  k3b_stats<<<8,           256, 0, stream>>>(ysum, musig);
  k4_norm  <<<16384,       256, 0, stream>>>(out, musig, gamma, beta);
}